// Round 18
// baseline (267.426 us; speedup 1.0000x reference)
//
#include <hip/hip_runtime.h>

#define D_MODEL 512
#define NHEADS 8
#define DH 64
#define BATCH 2
#define SEQ 4096
#define MTOT (BATCH*SEQ)   // 8192

typedef __attribute__((ext_vector_type(8))) short bf16x8;
typedef __attribute__((ext_vector_type(4))) short s16x4;
typedef __attribute__((ext_vector_type(4))) float f32x4;
typedef __attribute__((ext_vector_type(16))) float f32x16;

__device__ __forceinline__ unsigned short f2b(float f) {
  unsigned int u = __float_as_uint(f);
  u = (u + 0x7fffu + ((u >> 16) & 1u)) >> 16;
  return (unsigned short)u;
}

__device__ __forceinline__ float fexp2(float x) {
  return __builtin_amdgcn_exp2f(x);
}

__device__ __forceinline__ unsigned int cvtpk_bf16(float a, float b) {
  unsigned int r;
  asm("v_cvt_pk_bf16_f32 %0, %1, %2" : "=v"(r) : "v"(a), "v"(b));
  return r;
}

// hardware transpose read: tile_base = addr & ~127 (4x16 bf16 row-major tile),
// col = (addr>>3)&15; lane receives the 4 bf16 of that column. (r10-verified)
__device__ __forceinline__ void tr16(unsigned addr, s16x4& d) {
  asm volatile("ds_read_b64_tr_b16 %0, %1" : "=v"(d) : "v"(addr));
}

// ---------------- conversion kernels ----------------

__global__ void cvt_x_kernel(const float* __restrict__ X,
                             unsigned short* __restrict__ Xb, int n) {
  int i = (blockIdx.x * blockDim.x + threadIdx.x) * 8;
  if (i >= n) return;
  const float4* s = (const float4*)(X + i);
  float4 v0 = s[0], v1 = s[1];
  union { bf16x8 v; unsigned short u[8]; } r;
  r.u[0] = f2b(v0.x); r.u[1] = f2b(v0.y); r.u[2] = f2b(v0.z); r.u[3] = f2b(v0.w);
  r.u[4] = f2b(v1.x); r.u[5] = f2b(v1.y); r.u[6] = f2b(v1.z); r.u[7] = f2b(v1.w);
  *(bf16x8*)(Xb + i) = r.v;
}

__global__ void cvt_w_kernel(const float* __restrict__ W0, const float* __restrict__ W1,
                             const float* __restrict__ W2, const float* __restrict__ W3,
                             unsigned short* __restrict__ Wt) {
  const float* Ws[4] = {W0, W1, W2, W3};
  const float* W = Ws[blockIdx.y];
  int t = blockIdx.x * blockDim.x + threadIdx.x;
  int k = t >> 9, n = t & 511;
  Wt[(size_t)blockIdx.y * (512*512) + (size_t)n * 512 + k] = f2b(W[t]);
}

// ---------------- 128x128 bf16 MFMA GEMM ----------------
__global__ __launch_bounds__(256) void gemm128_kernel(
    const unsigned short* __restrict__ A,
    const unsigned short* __restrict__ WtAll,
    unsigned short* __restrict__ qkv,
    float* __restrict__ outF,
    int modeParam) {
  int mode = (modeParam < 0) ? (int)blockIdx.z : modeParam;
  const unsigned short* Wt = WtAll + (size_t)((modeParam < 0) ? blockIdx.z : 0) * (512*512);

  __shared__ __align__(16) unsigned short Alds[128][72];
  __shared__ __align__(16) unsigned short Blds[128][72];

  int t = threadIdx.x;
  int lane = t & 63, wave = t >> 6;
  int wr = wave >> 1, wc = wave & 1;
  int lr = lane & 15, lg = lane >> 4;
  int mBase = blockIdx.x * 128;
  int nBase = blockIdx.y * 128;

  f32x4 zero = {0.f, 0.f, 0.f, 0.f};
  f32x4 acc[4][4];
#pragma unroll
  for (int i = 0; i < 4; i++)
#pragma unroll
    for (int j = 0; j < 4; j++) acc[i][j] = zero;

  int seg = t & 7, r0 = t >> 3;

  for (int k0 = 0; k0 < 512; k0 += 64) {
#pragma unroll
    for (int p = 0; p < 4; ++p) {
      int row = r0 + p * 32;
      *(int4*)&Alds[row][seg * 8] =
          *(const int4*)(A + (size_t)(mBase + row) * 512 + k0 + seg * 8);
      *(int4*)&Blds[row][seg * 8] =
          *(const int4*)(Wt + (size_t)(nBase + row) * 512 + k0 + seg * 8);
    }
    __syncthreads();
#pragma unroll
    for (int kk = 0; kk < 64; kk += 32) {
      bf16x8 afr[4], bfr[4];
#pragma unroll
      for (int mi = 0; mi < 4; mi++)
        afr[mi] = *(const bf16x8*)&Alds[wr * 64 + mi * 16 + lr][kk + lg * 8];
#pragma unroll
      for (int ni = 0; ni < 4; ni++)
        bfr[ni] = *(const bf16x8*)&Blds[wc * 64 + ni * 16 + lr][kk + lg * 8];
#pragma unroll
      for (int mi = 0; mi < 4; mi++)
#pragma unroll
        for (int ni = 0; ni < 4; ni++)
          acc[mi][ni] = __builtin_amdgcn_mfma_f32_16x16x32_bf16(
              afr[mi], bfr[ni], acc[mi][ni], 0, 0, 0);
    }
    __syncthreads();
  }

#pragma unroll
  for (int mi = 0; mi < 4; mi++) {
#pragma unroll
    for (int ni = 0; ni < 4; ni++) {
#pragma unroll
      for (int rg = 0; rg < 4; rg++) {
        int r = mBase + wr * 64 + mi * 16 + lg * 4 + rg;
        int c = nBase + wc * 64 + ni * 16 + lr;
        float v = acc[mi][ni][rg];
        if (mode < 3) {
          int b = r >> 12, s = r & 4095, h = c >> 6, d = c & 63;
          qkv[(size_t)mode * ((size_t)MTOT * 512) +
              ((((size_t)b * NHEADS + h) * SEQ + s) * DH + d)] = f2b(v);
        } else {
          outF[(size_t)r * 512 + c] = v;
        }
      }
    }
  }
}

// ---------------- flash attention (32x32 MFMA + in-block KV-split) -----------
// grid 512 flat, block 512 (8 waves). Waves 0-3 (grp 0) process EVEN KV tiles,
// waves 4-7 (grp 1) ODD tiles, for the same 128 q-rows (lw = wave&3 selects a
// 32-q sub-chunk). Buffer pair: buf0 = even tile, buf1 = odd tile; each iter
// stages both, 1 barrier per tile. Per-tile math identical to r16 (proven).
// End: partner waves (w, w^4) merge online-softmax states; f32 scratch in
// then-dead Kl/Vl; group A normalizes + writes CTX.
__global__ __launch_bounds__(512) void attn_kernel(
    const unsigned short* __restrict__ Qb,
    const unsigned short* __restrict__ Kb,
    const unsigned short* __restrict__ Vb,
    unsigned short* __restrict__ CTX) {
  int flat = blockIdx.x;
  int xcd = flat & 7, jj = flat >> 3;
  int bh = xcd + ((jj >> 5) << 3);   // 2 heads per XCD, bijective (512%8==0)
  int qc = jj & 31;
  int b = bh >> 3, h = bh & 7;
  const unsigned short* Qp = Qb + (size_t)bh * SEQ * DH;
  const unsigned short* Kp = Kb + (size_t)bh * SEQ * DH;
  const unsigned short* Vp = Vb + (size_t)bh * SEQ * DH;

  __shared__ __align__(128) unsigned short Kl[2][64][72];   // 18432 B
  __shared__ __align__(128) unsigned short Vl[2][4096];     // 16384 B
  __shared__ __align__(128) unsigned short PT[8][32][72];   // 36864 B

  int t = threadIdx.x;                 // 0..511
  int lane = t & 63, wave = t >> 6;    // 8 waves
  int lw = wave & 3, grp = wave >> 2;  // q sub-chunk / KV half
  int q = lane & 31, hv = lane >> 5;
  int lr = lane & 15, lg2 = (lane >> 4) & 1;
  int q0w = qc * 128 + lw * 32;

  // Q fragments (B operand): col=q, k(dh) = s*16 + hv*8 + j
  bf16x8 aq[4];
#pragma unroll
  for (int s = 0; s < 4; s++)
    aq[s] = *(const bf16x8*)(Qp + (size_t)(q0w + q) * DH + s * 16 + hv * 8);

  f32x16 o0, o1;
#pragma unroll
  for (int i = 0; i < 16; i++) { o0[i] = 0.f; o1[i] = 0.f; }
  float m2 = -1e30f, lsum = 0.f;

  const float c2 = 0.125f * 1.44269504088896340736f;

  // staging: 512 threads, per iter stage BOTH tiles (K and V each): row=t>>3
  int srow = t >> 3, sseg = t & 7;
  int vdst = ((srow >> 2) * 4 + (sseg >> 1)) * 64 + (srow & 3) * 16 + (sseg & 1) * 8;
  const int NIT = SEQ / 128;   // 32 tile-pairs

  unsigned vtr_lane = (unsigned)(hv * 1024 + lg2 * 128 + lr * 8);
  unsigned vbuf = (unsigned)(size_t)&Vl[grp][0] + vtr_lane;

  // preload pair 0: tile p -> buf p (global row p*64 + srow)
  int4 kreg[2], vreg[2];
#pragma unroll
  for (int p = 0; p < 2; ++p) {
    kreg[p] = *(const int4*)(Kp + (size_t)(p * 64 + srow) * DH + sseg * 8);
    vreg[p] = *(const int4*)(Vp + (size_t)(p * 64 + srow) * DH + sseg * 8);
  }

  for (int it = 0; it < NIT; ++it) {
#pragma unroll
    for (int p = 0; p < 2; ++p) {
      *(int4*)&Kl[p][srow][sseg * 8] = kreg[p];
      *(int4*)&Vl[p][vdst] = vreg[p];
    }
    if (it + 1 < NIT) {
#pragma unroll
      for (int p = 0; p < 2; ++p) {
        int rowg = (it + 1) * 128 + p * 64 + srow;
        kreg[p] = *(const int4*)(Kp + (size_t)rowg * DH + sseg * 8);
        vreg[p] = *(const int4*)(Vp + (size_t)rowg * DH + sseg * 8);
      }
    }
    __syncthreads();   // pair staged

    // ---- per-tile math on buf[grp] (byte-identical to r16, cur -> grp) ----
    f32x16 s0, s1;
#pragma unroll
    for (int i = 0; i < 16; i++) { s0[i] = 0.f; s1[i] = 0.f; }
    __builtin_amdgcn_s_setprio(1);
#pragma unroll
    for (int s = 0; s < 4; s++) {
      bf16x8 bk0 = *(const bf16x8*)&Kl[grp][q][s * 16 + hv * 8];
      bf16x8 bk1 = *(const bf16x8*)&Kl[grp][32 + q][s * 16 + hv * 8];
      s0 = __builtin_amdgcn_mfma_f32_32x32x16_bf16(bk0, aq[s], s0, 0, 0, 0);
      s1 = __builtin_amdgcn_mfma_f32_32x32x16_bf16(bk1, aq[s], s1, 0, 0, 0);
    }
    __builtin_amdgcn_s_setprio(0);

    float pm;
    {
      float a0 = fmaxf(fmaxf(s0[0], s0[1]), fmaxf(s0[2], s0[3]));
      float a1 = fmaxf(fmaxf(s0[4], s0[5]), fmaxf(s0[6], s0[7]));
      float a2 = fmaxf(fmaxf(s0[8], s0[9]), fmaxf(s0[10], s0[11]));
      float a3 = fmaxf(fmaxf(s0[12], s0[13]), fmaxf(s0[14], s0[15]));
      float b0 = fmaxf(fmaxf(s1[0], s1[1]), fmaxf(s1[2], s1[3]));
      float b1 = fmaxf(fmaxf(s1[4], s1[5]), fmaxf(s1[6], s1[7]));
      float b2 = fmaxf(fmaxf(s1[8], s1[9]), fmaxf(s1[10], s1[11]));
      float b3 = fmaxf(fmaxf(s1[12], s1[13]), fmaxf(s1[14], s1[15]));
      pm = fmaxf(fmaxf(fmaxf(a0, a1), fmaxf(a2, a3)),
                 fmaxf(fmaxf(b0, b1), fmaxf(b2, b3))) * c2;
    }
    pm = fmaxf(pm, __shfl_xor(pm, 32));

    if (!__all((int)(pm <= m2 + 8.f))) {
      float mn = fmaxf(m2, pm);
      float corr = fexp2(m2 - mn);
      m2 = mn;
      lsum *= corr;
#pragma unroll
      for (int i = 0; i < 16; i++) { o0[i] *= corr; o1[i] *= corr; }
    }

    float rs = 0.f;
#pragma unroll
    for (int rg = 0; rg < 4; rg++) {
      float p0 = fexp2(fmaf(s0[rg * 4 + 0], c2, -m2));
      float p1 = fexp2(fmaf(s0[rg * 4 + 1], c2, -m2));
      float p2 = fexp2(fmaf(s0[rg * 4 + 2], c2, -m2));
      float p3 = fexp2(fmaf(s0[rg * 4 + 3], c2, -m2));
      rs += (p0 + p1) + (p2 + p3);
      uint2 w; w.x = cvtpk_bf16(p0, p1); w.y = cvtpk_bf16(p2, p3);
      *(uint2*)&PT[wave][q][rg * 8 + hv * 4] = w;
      float q0_ = fexp2(fmaf(s1[rg * 4 + 0], c2, -m2));
      float q1_ = fexp2(fmaf(s1[rg * 4 + 1], c2, -m2));
      float q2_ = fexp2(fmaf(s1[rg * 4 + 2], c2, -m2));
      float q3_ = fexp2(fmaf(s1[rg * 4 + 3], c2, -m2));
      rs += (q0_ + q1_) + (q2_ + q3_);
      uint2 w2; w2.x = cvtpk_bf16(q0_, q1_); w2.y = cvtpk_bf16(q2_, q3_);
      *(uint2*)&PT[wave][q][32 + rg * 8 + hv * 4] = w2;
    }
    rs += __shfl_xor(rs, 32);
    lsum += rs;

    bf16x8 ap[4];
#pragma unroll
    for (int s = 0; s < 4; s++)
      ap[s] = *(const bf16x8*)&PT[wave][q][s * 16 + hv * 8];

    {
      union { bf16x8 v; s16x4 hh[2]; } bv[4];
#pragma unroll
      for (int s = 0; s < 4; s++) {
        tr16(vbuf + s * 2048 + 0 * 512 + 0 * 256, bv[s].hh[0]);
        tr16(vbuf + s * 2048 + 1 * 512 + 0 * 256, bv[s].hh[1]);
      }
      asm volatile("s_waitcnt lgkmcnt(0)" ::: "memory");
      __builtin_amdgcn_sched_barrier(0);
      __builtin_amdgcn_s_setprio(1);
#pragma unroll
      for (int s = 0; s < 4; s++)
        o0 = __builtin_amdgcn_mfma_f32_32x32x16_bf16(bv[s].v, ap[s], o0, 0, 0, 0);
      __builtin_amdgcn_s_setprio(0);
    }
    {
      union { bf16x8 v; s16x4 hh[2]; } bv[4];
#pragma unroll
      for (int s = 0; s < 4; s++) {
        tr16(vbuf + s * 2048 + 0 * 512 + 1 * 256, bv[s].hh[0]);
        tr16(vbuf + s * 2048 + 1 * 512 + 1 * 256, bv[s].hh[1]);
      }
      asm volatile("s_waitcnt lgkmcnt(0)" ::: "memory");
      __builtin_amdgcn_sched_barrier(0);
      __builtin_amdgcn_s_setprio(1);
#pragma unroll
      for (int s = 0; s < 4; s++)
        o1 = __builtin_amdgcn_mfma_f32_32x32x16_bf16(bv[s].v, ap[s], o1, 0, 0, 0);
      __builtin_amdgcn_s_setprio(0);
    }
    __syncthreads();   // both groups done reading pair before next stage
  }

  // ---- merge partner waves (w, w^4): same q-rows, disjoint key halves ----
  float* mf = (float*)&PT[wave][0][0];          // 256 B patch inside own PT
  if (hv == 0) { mf[q] = m2; mf[32 + q] = lsum; }
  __syncthreads();
  float* pmf = (float*)&PT[wave ^ 4][0][0];
  float pm_ = pmf[q], pl_ = pmf[32 + q];
  float mm = fmaxf(m2, pm_);
  float sc = fexp2(m2 - mm);
  float psc = fexp2(pm_ - mm);
  float ltot = lsum * sc + pl_ * psc;

  // f32 scratch in dead Kl/Vl: 8 KB per lw (lw 0,1 -> Kl; lw 2,3 -> Vl)
  float* scr = (lw < 2) ? ((float*)&Kl[0][0][0] + lw * 2048)
                        : ((float*)&Vl[0][0] + (lw - 2) * 2048);
  if (grp == 1) {
#pragma unroll
    for (int i = 0; i < 16; i++) scr[i * 64 + lane] = o0[i] * sc;
#pragma unroll
    for (int i = 0; i < 16; i++) scr[(16 + i) * 64 + lane] = o1[i] * sc;
  }
  __syncthreads();
  if (grp == 0) {
    float inv = 1.f / ltot;
#pragma unroll
    for (int i = 0; i < 16; i++) o0[i] = (o0[i] * sc + scr[i * 64 + lane]) * inv;
#pragma unroll
    for (int i = 0; i < 16; i++) o1[i] = (o1[i] * sc + scr[(16 + i) * 64 + lane]) * inv;

    // epilogue (r16 pattern): transpose via PT, coalesced write
#pragma unroll
    for (int rg = 0; rg < 4; rg++) {
      uint2 w;
      w.x = cvtpk_bf16(o0[rg * 4 + 0], o0[rg * 4 + 1]);
      w.y = cvtpk_bf16(o0[rg * 4 + 2], o0[rg * 4 + 3]);
      *(uint2*)&PT[wave][q][rg * 8 + hv * 4] = w;
      uint2 w2;
      w2.x = cvtpk_bf16(o1[rg * 4 + 0], o1[rg * 4 + 1]);
      w2.y = cvtpk_bf16(o1[rg * 4 + 2], o1[rg * 4 + 3]);
      *(uint2*)&PT[wave][q][32 + rg * 8 + hv * 4] = w2;
    }
    int qr = lane >> 1, half = lane & 1;
    size_t base = ((size_t)(b * SEQ + q0w + qr)) * 512 + h * 64 + half * 32;
#pragma unroll
    for (int i = 0; i < 4; i++) {
      bf16x8 w = *(const bf16x8*)&PT[wave][qr][half * 32 + i * 8];
      *(bf16x8*)(CTX + base + i * 8) = w;
    }
  }
}

// ---------------- launch ----------------

extern "C" void kernel_launch(void* const* d_in, const int* in_sizes, int n_in,
                              void* d_out, int out_size, void* d_ws, size_t ws_size,
                              hipStream_t stream) {
  const float* X  = (const float*)d_in[0];
  const float* Wq = (const float*)d_in[1];
  const float* Wk = (const float*)d_in[2];
  const float* Wv = (const float*)d_in[3];
  const float* Wo = (const float*)d_in[4];
  float* out = (float*)d_out;

  char* ws = (char*)d_ws;
  unsigned short* Wqt = (unsigned short*)(ws);
  unsigned short* Wot = (unsigned short*)(ws + 3u * 524288u);
  unsigned short* Xb  = (unsigned short*)(ws + 4u * 524288u);
  unsigned short* Qb  = (unsigned short*)(ws + 4u * 524288u + 8388608u);
  unsigned short* Kb  = Qb + (size_t)MTOT * 512;
  unsigned short* Vb  = Kb + (size_t)MTOT * 512;
  unsigned short* CTX = Vb + (size_t)MTOT * 512;

  int nX = MTOT * D_MODEL;
  cvt_x_kernel<<<dim3(nX / (8 * 256)), dim3(256), 0, stream>>>(X, Xb, nX);
  cvt_w_kernel<<<dim3(1024, 4), dim3(256), 0, stream>>>(Wq, Wk, Wv, Wo, Wqt);
  gemm128_kernel<<<dim3(64, 4, 3), dim3(256), 0, stream>>>(Xb, Wqt, Qb, nullptr, -1);
  attn_kernel<<<dim3(512), dim3(512), 0, stream>>>(Qb, Kb, Vb, CTX);
  gemm128_kernel<<<dim3(64, 4, 1), dim3(256), 0, stream>>>(CTX, Wot, nullptr, out, 3);
}

// Round 19
// 189.924 us; speedup vs baseline: 1.4081x; 1.4081x over previous
//
#include <hip/hip_runtime.h>

#define D_MODEL 512
#define NHEADS 8
#define DH 64
#define BATCH 2
#define SEQ 4096
#define MTOT (BATCH*SEQ)   // 8192

typedef __attribute__((ext_vector_type(8))) short bf16x8;
typedef __attribute__((ext_vector_type(4))) short s16x4;
typedef __attribute__((ext_vector_type(4))) float f32x4;

// async global->LDS, width 16B: dest is wave-uniform base + lane*16 (HW rule)
#define GLDS16(src, dst) __builtin_amdgcn_global_load_lds( \
    (const __attribute__((address_space(1))) void*)(src),  \
    (__attribute__((address_space(3))) void*)(dst), 16, 0, 0)

__device__ __forceinline__ unsigned short f2b(float f) {
  unsigned int u = __float_as_uint(f);
  u = (u + 0x7fffu + ((u >> 16) & 1u)) >> 16;
  return (unsigned short)u;
}

__device__ __forceinline__ float fexp2(float x) {
  return __builtin_amdgcn_exp2f(x);
}

// pack 2 f32 -> 2 bf16 in one u32 (lo = a, hi = b)
__device__ __forceinline__ unsigned int cvtpk_bf16(float a, float b) {
  unsigned int r;
  asm("v_cvt_pk_bf16_f32 %0, %1, %2" : "=v"(r) : "v"(a), "v"(b));
  return r;
}

// hardware transpose read: tile_base = addr & ~127 (4x16 bf16 row-major tile),
// col = (addr>>3)&15; lane receives the 4 bf16 of that column. (r10-verified)
__device__ __forceinline__ void tr16(unsigned addr, s16x4& d) {
  asm volatile("ds_read_b64_tr_b16 %0, %1" : "=v"(d) : "v"(addr));
}

// ---------------- conversion kernels ----------------

__global__ void cvt_x_kernel(const float* __restrict__ X,
                             unsigned short* __restrict__ Xb, int n) {
  int i = (blockIdx.x * blockDim.x + threadIdx.x) * 8;
  if (i >= n) return;
  const float4* s = (const float4*)(X + i);
  float4 v0 = s[0], v1 = s[1];
  union { bf16x8 v; unsigned short u[8]; } r;
  r.u[0] = f2b(v0.x); r.u[1] = f2b(v0.y); r.u[2] = f2b(v0.z); r.u[3] = f2b(v0.w);
  r.u[4] = f2b(v1.x); r.u[5] = f2b(v1.y); r.u[6] = f2b(v1.z); r.u[7] = f2b(v1.w);
  *(bf16x8*)(Xb + i) = r.v;
}

__global__ void cvt_w_kernel(const float* __restrict__ W0, const float* __restrict__ W1,
                             const float* __restrict__ W2, const float* __restrict__ W3,
                             unsigned short* __restrict__ Wt) {
  const float* Ws[4] = {W0, W1, W2, W3};
  const float* W = Ws[blockIdx.y];
  int t = blockIdx.x * blockDim.x + threadIdx.x;
  int k = t >> 9, n = t & 511;
  Wt[(size_t)blockIdx.y * (512*512) + (size_t)n * 512 + k] = f2b(W[t]);
}

// ---------------- 128x128 bf16 MFMA GEMM (global_load_lds + XOR swizzle) -----
// LDS linear [128][64]; staging via global_load_lds width-16 with PRE-SWIZZLED
// global source (rule #21 both-sides): wave-issue groups are 8-row aligned so
// row&7 == lane>>3; write col8 = lane&7 holds global k-group (lane&7)^(lane>>3);
// reads use col8 = g ^ (row&7). Both sides at the b128 bank floor.
__global__ __launch_bounds__(256) void gemm128_kernel(
    const unsigned short* __restrict__ A,
    const unsigned short* __restrict__ WtAll,
    unsigned short* __restrict__ qkv,
    float* __restrict__ outF,
    int modeParam) {
  int mode = (modeParam < 0) ? (int)blockIdx.z : modeParam;
  const unsigned short* Wt = WtAll + (size_t)((modeParam < 0) ? blockIdx.z : 0) * (512*512);

  __shared__ __align__(128) unsigned short Alds[128][64];
  __shared__ __align__(128) unsigned short Blds[128][64];

  int t = threadIdx.x;
  int lane = t & 63, wave = t >> 6;
  int wr = wave >> 1, wc = wave & 1;
  int lr = lane & 15, lg = lane >> 4;
  int mBase = blockIdx.x * 128;
  int nBase = blockIdx.y * 128;

  // staging coords
  int lrow = lane >> 3;              // 0..7 (== row&7 of this lane's row)
  int swz8 = (lane & 7) ^ lrow;      // pre-swizzled global k-group

  f32x4 zero = {0.f, 0.f, 0.f, 0.f};
  f32x4 acc[4][4];
#pragma unroll
  for (int i = 0; i < 4; i++)
#pragma unroll
    for (int j = 0; j < 4; j++) acc[i][j] = zero;

  for (int k0 = 0; k0 < 512; k0 += 64) {
#pragma unroll
    for (int p = 0; p < 4; ++p) {
      int row0 = p * 32 + wave * 8;    // wave-uniform, 8-row aligned
      const unsigned short* sA =
          A + (size_t)(mBase + row0 + lrow) * 512 + k0 + swz8 * 8;
      const unsigned short* sB =
          Wt + (size_t)(nBase + row0 + lrow) * 512 + k0 + swz8 * 8;
      GLDS16(sA, &Alds[row0][0]);
      GLDS16(sB, &Blds[row0][0]);
    }
    __syncthreads();   // compiler drains vmcnt before barrier
#pragma unroll
    for (int kk = 0; kk < 64; kk += 32) {
      bf16x8 afr[4], bfr[4];
#pragma unroll
      for (int mi = 0; mi < 4; mi++) {
        int row = wr * 64 + mi * 16 + lr;
        afr[mi] = *(const bf16x8*)&Alds[row][(((kk >> 3) + lg) ^ (lr & 7)) * 8];
      }
#pragma unroll
      for (int ni = 0; ni < 4; ni++) {
        int row = wc * 64 + ni * 16 + lr;
        bfr[ni] = *(const bf16x8*)&Blds[row][(((kk >> 3) + lg) ^ (lr & 7)) * 8];
      }
#pragma unroll
      for (int mi = 0; mi < 4; mi++)
#pragma unroll
        for (int ni = 0; ni < 4; ni++)
          acc[mi][ni] = __builtin_amdgcn_mfma_f32_16x16x32_bf16(
              afr[mi], bfr[ni], acc[mi][ni], 0, 0, 0);
    }
    __syncthreads();
  }

  // epilogue. C/D layout: col = lane&15, row = 4*(lane>>4) + reg  [HW-measured]
#pragma unroll
  for (int mi = 0; mi < 4; mi++) {
#pragma unroll
    for (int ni = 0; ni < 4; ni++) {
#pragma unroll
      for (int rg = 0; rg < 4; rg++) {
        int r = mBase + wr * 64 + mi * 16 + lg * 4 + rg;
        int c = nBase + wc * 64 + ni * 16 + lr;
        float v = acc[mi][ni][rg];
        if (mode < 3) {
          int b = r >> 12, s = r & 4095, h = c >> 6, d = c & 63;
          qkv[(size_t)mode * ((size_t)MTOT * 512) +
              ((((size_t)b * NHEADS + h) * SEQ + s) * DH + d)] = f2b(v);
        } else {
          outF[(size_t)r * 512 + c] = v;
        }
      }
    }
  }
}

// ---------------- flash attention (r15-proven, byte-identical) ---------------
// grid 512 flat, block 512 (8 waves), 16 q-rows/wave. KV tiles of 64 keys,
// K row-major LDS + V subtiled LDS, double-buffered; ONE barrier per tile.
// Swapped-QK lane-local softmax; T13 defer-max; tr16 V fragments; T5 setprio.
__global__ __launch_bounds__(512) void attn_kernel(
    const unsigned short* __restrict__ Qb,
    const unsigned short* __restrict__ Kb,
    const unsigned short* __restrict__ Vb,
    unsigned short* __restrict__ CTX) {
  int flat = blockIdx.x;
  int xcd = flat & 7, jj = flat >> 3;
  int bh = xcd + ((jj >> 5) << 3);   // 2 heads per XCD, bijective (512%8==0)
  int qc = jj & 31;
  int b = bh >> 3, h = bh & 7;
  const unsigned short* Qp = Qb + (size_t)bh * SEQ * DH;
  const unsigned short* Kp = Kb + (size_t)bh * SEQ * DH;
  const unsigned short* Vp = Vb + (size_t)bh * SEQ * DH;

  __shared__ __align__(128) unsigned short Kl[2][64][72];   // 18432 B
  __shared__ __align__(128) unsigned short Vl[2][4096];     // 16384 B
  __shared__ __align__(128) unsigned short PT[8][16][72];   // 18432 B

  int t = threadIdx.x;            // 0..511
  int lane = t & 63, wave = t >> 6;
  int lr = lane & 15, lg = lane >> 4;
  int q0 = qc * 128 + wave * 16;

  // Q fragments (B operand): col=q=lr, k = kk*32 + 8*lg + j
  bf16x8 aq[2];
#pragma unroll
  for (int kk = 0; kk < 2; ++kk)
    aq[kk] = *(const bf16x8*)(Qp + (size_t)(q0 + lr) * DH + kk * 32 + lg * 8);

  f32x4 zero = {0.f, 0.f, 0.f, 0.f};
  f32x4 o[4];
#pragma unroll
  for (int dt = 0; dt < 4; dt++) o[dt] = zero;
  float m2 = -1e30f, lsum = 0.f;

  const float c2 = 0.125f * 1.44269504088896340736f;

  // V staging: 512 threads, ONE b128 each: row = t>>3, seg = t&7
  int srow = t >> 3, sseg = t & 7;
  int vdst = ((srow >> 2) * 4 + (sseg >> 1)) * 64 + (srow & 3) * 16 + (sseg & 1) * 8;
  const int NT = SEQ / 64;

  unsigned vtr_lane = (unsigned)(lg * 1024 + lr * 8);
  unsigned vbuf0 = (unsigned)(size_t)&Vl[0][0];
  unsigned vbuf1 = (unsigned)(size_t)&Vl[1][0];

  // preload tile 0
  int4 kreg = *(const int4*)(Kp + (size_t)srow * DH + sseg * 8);
  int4 vreg = *(const int4*)(Vp + (size_t)srow * DH + sseg * 8);

  for (int kb = 0; kb < NT; ++kb) {
    int cur = kb & 1;
    *(int4*)&Kl[cur][srow][sseg * 8] = kreg;
    *(int4*)&Vl[cur][vdst] = vreg;
    if (kb + 1 < NT) {
      kreg = *(const int4*)(Kp + (size_t)((kb + 1) * 64 + srow) * DH + sseg * 8);
      vreg = *(const int4*)(Vp + (size_t)((kb + 1) * 64 + srow) * DH + sseg * 8);
    }
    __syncthreads();   // buf[cur] staged; kb-2 readers proven past barrier(kb-1)

    // QK^T swapped: sacc[nt][r] = S[key = nt*16 + 4*lg + r][q = lr]
    f32x4 sacc[4];
    __builtin_amdgcn_s_setprio(1);
#pragma unroll
    for (int nt = 0; nt < 4; nt++) {
      sacc[nt] = zero;
#pragma unroll
      for (int kk = 0; kk < 2; kk++) {
        bf16x8 bk = *(const bf16x8*)&Kl[cur][nt * 16 + lr][kk * 32 + lg * 8];
        sacc[nt] = __builtin_amdgcn_mfma_f32_16x16x32_bf16(bk, aq[kk], sacc[nt], 0, 0, 0);
      }
    }
    __builtin_amdgcn_s_setprio(0);

    // lane-local softmax (base-2)
    float pm;
    {
      float a0 = fmaxf(fmaxf(sacc[0][0], sacc[0][1]), fmaxf(sacc[0][2], sacc[0][3]));
      float a1 = fmaxf(fmaxf(sacc[1][0], sacc[1][1]), fmaxf(sacc[1][2], sacc[1][3]));
      float a2 = fmaxf(fmaxf(sacc[2][0], sacc[2][1]), fmaxf(sacc[2][2], sacc[2][3]));
      float a3 = fmaxf(fmaxf(sacc[3][0], sacc[3][1]), fmaxf(sacc[3][2], sacc[3][3]));
      pm = fmaxf(fmaxf(a0, a1), fmaxf(a2, a3)) * c2;
    }
    pm = fmaxf(pm, __shfl_xor(pm, 16));
    pm = fmaxf(pm, __shfl_xor(pm, 32));

    // T13 defer-max
    if (!__all((int)(pm <= m2 + 8.f))) {
      float mn = fmaxf(m2, pm);
      float corr = fexp2(m2 - mn);
      m2 = mn;
      lsum *= corr;
#pragma unroll
      for (int dt = 0; dt < 4; dt++) {
        f32x4 tmp = o[dt];
        tmp[0] *= corr; tmp[1] *= corr; tmp[2] *= corr; tmp[3] *= corr;
        o[dt] = tmp;
      }
    }

    float p[4][4];
    float rs = 0.f;
#pragma unroll
    for (int nt = 0; nt < 4; nt++)
#pragma unroll
      for (int r = 0; r < 4; r++) {
        float v = fexp2(fmaf(sacc[nt][r], c2, -m2));
        p[nt][r] = v;
        rs += v;
      }
    rs += __shfl_xor(rs, 16);
    rs += __shfl_xor(rs, 32);
    lsum += rs;

    // pack P -> PT[q][key] as b64 (per-wave; intra-wave in-order, no barrier)
#pragma unroll
    for (int nt = 0; nt < 4; nt++) {
      uint2 w;
      w.x = cvtpk_bf16(p[nt][0], p[nt][1]);
      w.y = cvtpk_bf16(p[nt][2], p[nt][3]);
      *(uint2*)&PT[wave][lr][nt * 16 + lg * 4] = w;
    }

    bf16x8 ap[2];
#pragma unroll
    for (int ks = 0; ks < 2; ks++)
      ap[ks] = *(const bf16x8*)&PT[wave][lr][ks * 32 + lg * 8];

    // PV: O^T += V^T * P^T; V^T fragments via hw transpose reads
    unsigned vb = (cur ? vbuf1 : vbuf0) + vtr_lane;
    union { bf16x8 v; s16x4 hh[2]; } bv[4][2];
#pragma unroll
    for (int dt = 0; dt < 4; dt++)
#pragma unroll
      for (int ks = 0; ks < 2; ks++) {
        tr16(vb + ks * 4096 + 0 * 512 + dt * 128, bv[dt][ks].hh[0]);
        tr16(vb + ks * 4096 + 1 * 512 + dt * 128, bv[dt][ks].hh[1]);
      }
    asm volatile("s_waitcnt lgkmcnt(0)" ::: "memory");
    __builtin_amdgcn_sched_barrier(0);
    __builtin_amdgcn_s_setprio(1);
#pragma unroll
    for (int dt = 0; dt < 4; dt++)
#pragma unroll
      for (int ks = 0; ks < 2; ks++)
        o[dt] = __builtin_amdgcn_mfma_f32_16x16x32_bf16(bv[dt][ks].v, ap[ks], o[dt], 0, 0, 0);
    __builtin_amdgcn_s_setprio(0);
    // no trailing barrier: next tile writes the other buffer
  }

  // epilogue: normalize, transpose O via PT, coalesced write
  float inv = 1.f / lsum;
#pragma unroll
  for (int dt = 0; dt < 4; dt++) {
    uint2 w;
    w.x = cvtpk_bf16(o[dt][0] * inv, o[dt][1] * inv);
    w.y = cvtpk_bf16(o[dt][2] * inv, o[dt][3] * inv);
    *(uint2*)&PT[wave][lr][dt * 16 + lg * 4] = w;
  }

  int row = lane >> 2, cs = lane & 3;
  bf16x8 w0 = *(const bf16x8*)&PT[wave][row][cs * 16];
  bf16x8 w1 = *(const bf16x8*)&PT[wave][row][cs * 16 + 8];
  size_t base = ((size_t)(b * SEQ + q0 + row)) * 512 + h * 64 + cs * 16;
  *(bf16x8*)(CTX + base) = w0;
  *(bf16x8*)(CTX + base + 8) = w1;
}

// ---------------- launch ----------------

extern "C" void kernel_launch(void* const* d_in, const int* in_sizes, int n_in,
                              void* d_out, int out_size, void* d_ws, size_t ws_size,
                              hipStream_t stream) {
  const float* X  = (const float*)d_in[0];
  const float* Wq = (const float*)d_in[1];
  const float* Wk = (const float*)d_in[2];
  const float* Wv = (const float*)d_in[3];
  const float* Wo = (const float*)d_in[4];
  float* out = (float*)d_out;

  char* ws = (char*)d_ws;
  unsigned short* Wqt = (unsigned short*)(ws);
  unsigned short* Wot = (unsigned short*)(ws + 3u * 524288u);
  unsigned short* Xb  = (unsigned short*)(ws + 4u * 524288u);
  unsigned short* Qb  = (unsigned short*)(ws + 4u * 524288u + 8388608u);
  unsigned short* Kb  = Qb + (size_t)MTOT * 512;
  unsigned short* Vb  = Kb + (size_t)MTOT * 512;
  unsigned short* CTX = Vb + (size_t)MTOT * 512;

  int nX = MTOT * D_MODEL;
  cvt_x_kernel<<<dim3(nX / (8 * 256)), dim3(256), 0, stream>>>(X, Xb, nX);
  cvt_w_kernel<<<dim3(1024, 4), dim3(256), 0, stream>>>(Wq, Wk, Wv, Wo, Wqt);
  gemm128_kernel<<<dim3(64, 4, 3), dim3(256), 0, stream>>>(Xb, Wqt, Qb, nullptr, -1);
  attn_kernel<<<dim3(512), dim3(512), 0, stream>>>(Qb, Kb, Vb, CTX);
  gemm128_kernel<<<dim3(64, 4, 1), dim3(256), 0, stream>>>(CTX, Wot, nullptr, out, 3);
}